// Round 1
// baseline (6667.155 us; speedup 1.0000x reference)
//
#include <hip/hip_runtime.h>
#include <hip/hip_bf16.h>
#include <cstdint>
#include <cstddef>

#define LNUM 12
#define NH 12
#define CDIM 768
#define HDIM 64
#define TSEQ 1024
#define BSZ 2
#define MROWS 2048   // B*T
#define VOCAB 50257

typedef __attribute__((ext_vector_type(8))) short short8;
typedef __attribute__((ext_vector_type(4))) float f32x4;

// ---------------- embedding: x = wte[idx] + wpe[t] ----------------
__global__ __launch_bounds__(256)
void embed_kernel(const int* __restrict__ idx,
                  const float* __restrict__ wte,
                  const float* __restrict__ wpe,
                  float* __restrict__ x) {
  int row = blockIdx.x;            // 0..2047  (b*T + t)
  int t = row & (TSEQ - 1);
  int id = idx[row];
  const float* we = wte + (size_t)id * CDIM;
  const float* wp = wpe + (size_t)t * CDIM;
  float* xr = x + (size_t)row * CDIM;
  for (int c = threadIdx.x; c < CDIM; c += 256)
    xr[c] = we[c] + wp[c];
}

// ---------------- layernorm: fp32 in -> bf16 out ----------------
__global__ __launch_bounds__(256)
void ln_kernel(const float* __restrict__ x, const float* __restrict__ w,
               const float* __restrict__ b, __hip_bfloat16* __restrict__ out) {
  int row = blockIdx.x;
  int tid = threadIdx.x;
  const float* xr = x + (size_t)row * CDIM;
  float v0 = xr[tid], v1 = xr[tid + 256], v2 = xr[tid + 512];
  float s = v0 + v1 + v2;
  float ss = v0 * v0 + v1 * v1 + v2 * v2;
#pragma unroll
  for (int off = 32; off > 0; off >>= 1) {
    s += __shfl_xor(s, off, 64);
    ss += __shfl_xor(ss, off, 64);
  }
  __shared__ float red[8];
  int lane = tid & 63, wid = tid >> 6;
  if (lane == 0) { red[wid] = s; red[4 + wid] = ss; }
  __syncthreads();
  s = red[0] + red[1] + red[2] + red[3];
  ss = red[4] + red[5] + red[6] + red[7];
  float mu = s * (1.f / CDIM);
  float var = ss * (1.f / CDIM) - mu * mu;
  float rstd = rsqrtf(var + 1e-5f);
  __hip_bfloat16* orow = out + (size_t)row * CDIM;
  orow[tid]       = __float2bfloat16((v0 - mu) * rstd * w[tid]       + b[tid]);
  orow[tid + 256] = __float2bfloat16((v1 - mu) * rstd * w[tid + 256] + b[tid + 256]);
  orow[tid + 512] = __float2bfloat16((v2 - mu) * rstd * w[tid + 512] + b[tid + 512]);
}

// ------- weight transpose+convert: fp32 W[K,N] -> bf16 Wt[N,K] -------
__global__ __launch_bounds__(256)
void convT_kernel(const float* __restrict__ W, __hip_bfloat16* __restrict__ Wt,
                  int K, int N) {
  __shared__ float tile[32][33];
  int n0 = blockIdx.x * 32;
  int k0 = blockIdx.y * 32;
  int tx = threadIdx.x & 31;
  int ty = threadIdx.x >> 5;  // 0..7
#pragma unroll
  for (int i = 0; i < 4; i++) {
    int k = k0 + ty + i * 8;
    int n = n0 + tx;
    float v = 0.f;
    if (k < K && n < N) v = W[(size_t)k * N + n];
    tile[ty + i * 8][tx] = v;
  }
  __syncthreads();
#pragma unroll
  for (int i = 0; i < 4; i++) {
    int n = n0 + ty + i * 8;
    int k = k0 + tx;
    if (n < N && k < K)
      Wt[(size_t)n * K + k] = __float2bfloat16(tile[tx][ty + i * 8]);
  }
}

// ---------------- MFMA GEMM: C[M,N] = A[M,K] @ Wt[N,K]^T + bias ----------------
// MODE 1: gelu -> bf16 out_b      MODE 2: out_f += val (fp32 residual)
// MODE 3: qkv scatter -> Qf/Ktf/Vf fp32   MODE 4: raw fp32 out_f (no bias)
template <int MODE>
__global__ __launch_bounds__(256)
void gemm_kernel(const __hip_bfloat16* __restrict__ A,
                 const __hip_bfloat16* __restrict__ Wt,
                 const float* __restrict__ bias,
                 int K, int N,
                 float* __restrict__ out_f,
                 __hip_bfloat16* __restrict__ out_b,
                 float* __restrict__ Qf,
                 float* __restrict__ Ktf,
                 float* __restrict__ Vf) {
  __shared__ short a_sh[128 * 32];
  __shared__ short b_sh[128 * 32];
  int tid = threadIdx.x;
  int m0 = blockIdx.y * 128;
  int n0 = blockIdx.x * 128;
  int lane = tid & 63;
  int wv = tid >> 6;
  int wm = (wv >> 1) * 64, wn = (wv & 1) * 64;

  f32x4 acc[4][4];
  f32x4 zero4 = {0.f, 0.f, 0.f, 0.f};
#pragma unroll
  for (int i = 0; i < 4; i++)
#pragma unroll
    for (int j = 0; j < 4; j++) acc[i][j] = zero4;

  int srow = tid >> 1;          // 0..127
  int skh = (tid & 1) * 16;     // element offset within the 32-wide k-tile

  const short* Ap = (const short*)A;
  const short* Wp = (const short*)Wt;

  for (int k0 = 0; k0 < K; k0 += 32) {
    // stage A tile [128 x 32]
    const short* ag = Ap + (size_t)(m0 + srow) * K + k0 + skh;
    short8 av0 = *(const short8*)(ag);
    short8 av1 = *(const short8*)(ag + 8);
    *(short8*)(&a_sh[srow * 32 + skh]) = av0;
    *(short8*)(&a_sh[srow * 32 + skh + 8]) = av1;
    // stage B tile [128 x 32] from Wt[N,K]
    int nrow = n0 + srow;
    short8 bv0 = {0, 0, 0, 0, 0, 0, 0, 0};
    short8 bv1 = {0, 0, 0, 0, 0, 0, 0, 0};
    if (nrow < N) {
      const short* bg = Wp + (size_t)nrow * K + k0 + skh;
      bv0 = *(const short8*)(bg);
      bv1 = *(const short8*)(bg + 8);
    }
    *(short8*)(&b_sh[srow * 32 + skh]) = bv0;
    *(short8*)(&b_sh[srow * 32 + skh + 8]) = bv1;
    __syncthreads();
    // compute: 4x4 of 16x16x32 MFMA per wave (64x64 per wave)
    int arow = wm + (lane & 15);
    int brow = wn + (lane & 15);
    int kq = (lane >> 4) * 8;
    short8 af[4], bf[4];
#pragma unroll
    for (int i = 0; i < 4; i++) {
      af[i] = *(const short8*)(&a_sh[(arow + i * 16) * 32 + kq]);
      bf[i] = *(const short8*)(&b_sh[(brow + i * 16) * 32 + kq]);
    }
#pragma unroll
    for (int i = 0; i < 4; i++)
#pragma unroll
      for (int j = 0; j < 4; j++)
        acc[i][j] = __builtin_amdgcn_mfma_f32_16x16x32_bf16(af[i], bf[j], acc[i][j], 0, 0, 0);
    __syncthreads();
  }

  // epilogue: C/D layout (verified m89): col = lane&15, row = (lane>>4)*4 + r
  int row0 = (lane >> 4) * 4;
  int col0 = lane & 15;
#pragma unroll
  for (int i = 0; i < 4; i++) {
#pragma unroll
    for (int j = 0; j < 4; j++) {
#pragma unroll
      for (int r = 0; r < 4; r++) {
        int m = m0 + wm + i * 16 + row0 + r;
        int n = n0 + wn + j * 16 + col0;
        if (n >= N) continue;
        float val = acc[i][j][r];
        if (MODE != 4) val += bias[n];
        if (MODE == 1) {
          float u = val;
          float g = 0.5f * u * (1.f + tanhf(0.7978845608028654f * (u + 0.044715f * u * u * u)));
          out_b[(size_t)m * N + n] = __float2bfloat16(g);
        } else if (MODE == 2) {
          out_f[(size_t)m * N + n] += val;
        } else if (MODE == 3) {
          int b_ = m >> 10, t = m & 1023;
          if (n < 768) {
            int h = n >> 6, d = n & 63;
            Qf[(((size_t)(b_ * NH + h)) * TSEQ + t) * HDIM + d] = val;
          } else if (n < 1536) {
            int u2 = n - 768;
            int h = u2 >> 6, d = u2 & 63;
            Ktf[(((size_t)(b_ * NH + h)) * HDIM + d) * TSEQ + t] = val;
          } else {
            int u2 = n - 1536;
            int h = u2 >> 6, d = u2 & 63;
            Vf[(((size_t)(b_ * NH + h)) * TSEQ + t) * HDIM + d] = val;
          }
        } else {  // MODE 4
          out_f[(size_t)m * (size_t)N + n] = val;
        }
      }
    }
  }
}

// ---------------- attention: wave per query row, scores in LDS ----------------
__global__ __launch_bounds__(256)
void attn_kernel(const float* __restrict__ Qf, const float* __restrict__ Ktf,
                 const float* __restrict__ Vf, __hip_bfloat16* __restrict__ y) {
  __shared__ float q_sh[4][HDIM];
  __shared__ float s_sh[4][TSEQ];
  int tid = threadIdx.x;
  int lane = tid & 63, wid = tid >> 6;
  int row = blockIdx.x * 4 + wid;  // 0..24575  ((b*NH+h)*T + qt)
  int qt = row & (TSEQ - 1);
  int bh = row >> 10;
  const float* Kb = Ktf + (size_t)bh * HDIM * TSEQ;  // [d][t]
  const float* Vb = Vf + (size_t)bh * TSEQ * HDIM;   // [t][d]
  q_sh[wid][lane] = Qf[(size_t)row * HDIM + lane] * 0.125f;  // 1/sqrt(64)
  __syncthreads();

  int nk = qt + 1;
  float lmax = -1e30f;
  for (int kb = 0; kb < nk; kb += 64) {
    int k = kb + lane;
    float sc = -1e30f;
    if (k < nk) {
      float accd = 0.f;
      const float* kp = Kb + k;
#pragma unroll 16
      for (int d = 0; d < HDIM; d++)
        accd += q_sh[wid][d] * kp[(size_t)d * TSEQ];
      sc = accd;
    }
    s_sh[wid][kb + lane] = sc;
    lmax = fmaxf(lmax, sc);
  }
#pragma unroll
  for (int off = 32; off > 0; off >>= 1)
    lmax = fmaxf(lmax, __shfl_xor(lmax, off, 64));
  __syncthreads();

  float lsum = 0.f;
  for (int k = lane; k < nk; k += 64) {
    float e = __expf(s_sh[wid][k] - lmax);
    s_sh[wid][k] = e;
    lsum += e;
  }
#pragma unroll
  for (int off = 32; off > 0; off >>= 1)
    lsum += __shfl_xor(lsum, off, 64);
  __syncthreads();

  float accd = 0.f;
#pragma unroll 4
  for (int k = 0; k < nk; k++)
    accd += s_sh[wid][k] * Vb[(size_t)k * HDIM + lane];
  float o = accd / lsum;

  int b_ = bh / NH, h = bh % NH;
  y[((size_t)(b_ * TSEQ + qt)) * CDIM + h * HDIM + lane] = __float2bfloat16(o);
}

extern "C" void kernel_launch(void* const* d_in, const int* in_sizes, int n_in,
                              void* d_out, int out_size, void* d_ws, size_t ws_size,
                              hipStream_t stream) {
  (void)in_sizes; (void)n_in; (void)out_size;
  const int* idx       = (const int*)d_in[0];
  const float* wte     = (const float*)d_in[1];
  const float* wpe     = (const float*)d_in[2];
  const float* ln1_w   = (const float*)d_in[3];
  const float* ln1_b   = (const float*)d_in[4];
  const float* attn_w  = (const float*)d_in[5];
  const float* attn_b  = (const float*)d_in[6];
  const float* proj_w  = (const float*)d_in[7];
  const float* proj_b  = (const float*)d_in[8];
  const float* ln2_w   = (const float*)d_in[9];
  const float* ln2_b   = (const float*)d_in[10];
  const float* fc_w    = (const float*)d_in[11];
  const float* fc_b    = (const float*)d_in[12];
  const float* fcproj_w = (const float*)d_in[13];
  const float* fcproj_b = (const float*)d_in[14];
  const float* lnf_w   = (const float*)d_in[15];
  const float* lnf_b   = (const float*)d_in[16];
  const float* lm_head_w = (const float*)d_in[17];
  float* out = (float*)d_out;

  char* ws = (char*)d_ws;
  size_t off = 0;
  auto alloc = [&](size_t bytes) {
    char* p = ws + off;
    off = (off + bytes + 255) & ~(size_t)255;
    return p;
  };
  float* x            = (float*)alloc((size_t)MROWS * CDIM * 4);
  __hip_bfloat16* xb  = (__hip_bfloat16*)alloc((size_t)MROWS * CDIM * 2);
  float* Qf           = (float*)alloc((size_t)MROWS * CDIM * 4);
  float* Ktf          = (float*)alloc((size_t)MROWS * CDIM * 4);
  float* Vf           = (float*)alloc((size_t)MROWS * CDIM * 4);
  __hip_bfloat16* yb  = (__hip_bfloat16*)alloc((size_t)MROWS * CDIM * 2);
  __hip_bfloat16* hb  = (__hip_bfloat16*)alloc((size_t)MROWS * 4 * CDIM * 2);
  __hip_bfloat16* Wt  = (__hip_bfloat16*)alloc((size_t)VOCAB * CDIM * 2);
  if (off > ws_size) return;  // workspace too small — fail loudly via wrong output

  dim3 blk(256);
  embed_kernel<<<MROWS, blk, 0, stream>>>(idx, wte, wpe, x);

  for (int l = 0; l < LNUM; l++) {
    // attn block
    ln_kernel<<<MROWS, blk, 0, stream>>>(x, ln1_w + l * CDIM, ln1_b + l * CDIM, xb);
    convT_kernel<<<dim3((3 * CDIM) / 32, CDIM / 32), blk, 0, stream>>>(
        attn_w + (size_t)l * CDIM * 3 * CDIM, Wt, CDIM, 3 * CDIM);
    gemm_kernel<3><<<dim3((3 * CDIM) / 128, MROWS / 128), blk, 0, stream>>>(
        xb, Wt, attn_b + l * 3 * CDIM, CDIM, 3 * CDIM,
        nullptr, nullptr, Qf, Ktf, Vf);
    attn_kernel<<<(BSZ * NH * TSEQ) / 4, blk, 0, stream>>>(Qf, Ktf, Vf, yb);
    convT_kernel<<<dim3(CDIM / 32, CDIM / 32), blk, 0, stream>>>(
        proj_w + (size_t)l * CDIM * CDIM, Wt, CDIM, CDIM);
    gemm_kernel<2><<<dim3(CDIM / 128, MROWS / 128), blk, 0, stream>>>(
        yb, Wt, proj_b + l * CDIM, CDIM, CDIM,
        x, nullptr, nullptr, nullptr, nullptr);
    // mlp block
    ln_kernel<<<MROWS, blk, 0, stream>>>(x, ln2_w + l * CDIM, ln2_b + l * CDIM, xb);
    convT_kernel<<<dim3((4 * CDIM) / 32, CDIM / 32), blk, 0, stream>>>(
        fc_w + (size_t)l * CDIM * 4 * CDIM, Wt, CDIM, 4 * CDIM);
    gemm_kernel<1><<<dim3((4 * CDIM) / 128, MROWS / 128), blk, 0, stream>>>(
        xb, Wt, fc_b + l * 4 * CDIM, CDIM, 4 * CDIM,
        nullptr, hb, nullptr, nullptr, nullptr);
    convT_kernel<<<dim3(CDIM / 32, (4 * CDIM) / 32), blk, 0, stream>>>(
        fcproj_w + (size_t)l * 4 * CDIM * CDIM, Wt, 4 * CDIM, CDIM);
    gemm_kernel<2><<<dim3(CDIM / 128, MROWS / 128), blk, 0, stream>>>(
        hb, Wt, fcproj_b + l * CDIM, 4 * CDIM, CDIM,
        x, nullptr, nullptr, nullptr, nullptr);
  }

  ln_kernel<<<MROWS, blk, 0, stream>>>(x, lnf_w, lnf_b, xb);
  convT_kernel<<<dim3((VOCAB + 31) / 32, CDIM / 32), blk, 0, stream>>>(
      lm_head_w, Wt, CDIM, VOCAB);
  gemm_kernel<4><<<dim3((VOCAB + 127) / 128, MROWS / 128), blk, 0, stream>>>(
      xb, Wt, nullptr, CDIM, VOCAB,
      out, nullptr, nullptr, nullptr, nullptr);
}